// Round 5
// baseline (487.926 us; speedup 1.0000x reference)
//
#include <hip/hip_runtime.h>
#include <stdint.h>

// Problem constants
#define BB    64
#define CC    100
#define NBPER 150
#define FEAT  2052
#define KP    2112      // FEAT padded to 33*64 for BK=64 MFMA loop
#define NOUT  2048
#define MR    6400      // BB*CC rows of x / support

typedef __attribute__((ext_vector_type(8))) short   short8;
typedef __attribute__((ext_vector_type(4))) float   floatx4;

__device__ __forceinline__ unsigned short f2bf(float f) {
  unsigned int u = __float_as_uint(f);
  u += 0x7FFFu + ((u >> 16) & 1u);   // RNE
  return (unsigned short)(u >> 16);
}

// async global->LDS, 16B per lane. LDS dest is wave-uniform base; HW does base + lane*16.
__device__ __forceinline__ void async16(const void* g, void* l) {
  __builtin_amdgcn_global_load_lds((__attribute__((address_space(1))) void*)(g),
                                   (__attribute__((address_space(3))) void*)(l),
                                   16, 0, 0);
}

// ---------------------------------------------------------------------------
// K_PREP: dual-role kernel (one launch instead of two).
//   blocks [0, 4224):      gc_w [2052][2048] fp32 -> gcwT [2048][2112] bf16
//   blocks [4224, 10624):  bucket + x[b,c,:] build -> xbf bf16 [6400][2112]
// ---------------------------------------------------------------------------
__global__ __launch_bounds__(256) void k_prep(const float* __restrict__ gcw,
                                              unsigned short* __restrict__ gcwT,
                                              const float* __restrict__ imgf,
                                              const float* __restrict__ bbox,
                                              const float* __restrict__ lw,
                                              const float* __restrict__ lb,
                                              const int* __restrict__ labels,
                                              unsigned short* __restrict__ xbf) {
  __shared__ float tile[32][33];
  __shared__ int lab[NBPER];
  __shared__ int sidx[3];
  const int bx = blockIdx.x;
  const int tid = threadIdx.x;

  if (bx < 4224) {
    // ---- transpose role ----
    const int ko = bx % 66;
    const int oo = bx / 66;
    const int tx = tid & 31, ty = tid >> 5;
#pragma unroll
    for (int i = 0; i < 4; ++i) {
      const int k = ko * 32 + ty + i * 8;
      const int o = oo * 32 + tx;
      tile[ty + i * 8][tx] = (k < FEAT) ? gcw[(size_t)k * NOUT + o] : 0.f;
    }
    __syncthreads();
#pragma unroll
    for (int i = 0; i < 4; ++i) {
      const int o = oo * 32 + ty + i * 8;
      const int k = ko * 32 + tx;
      gcwT[(size_t)o * KP + k] = f2bf(tile[tx][ty + i * 8]);
    }
    return;
  }

  // ---- buildx role ----
  const int r2 = bx - 4224;
  const int b = r2 / 100;
  const int c = r2 - b * 100;
  if (tid < NBPER) lab[tid] = labels[b * NBPER + tid];
  __syncthreads();
  if (tid == 0) {
    int cnt = 0; sidx[0] = -1; sidx[1] = -1; sidx[2] = -1;
    for (int i = 0; i < NBPER; ++i)
      if (lab[i] == c + 1 && cnt < 3) { sidx[cnt] = b * NBPER + i; ++cnt; }
  }
  __syncthreads();
  const int r = b * CC + c;
  const int i0 = sidx[0], i1 = sidx[1], i2 = sidx[2];
  const float w0 = lw[0], w1 = lw[1], w2 = lw[2], bias = lb[0];
  for (int s = tid; s < KP / 8; s += 256) {
    const int d0 = s * 8;
    float v[8];
#pragma unroll
    for (int q = 0; q < 8; ++q) v[q] = 0.f;
    if (d0 < 2048) {
      if (i0 >= 0) {
        const float4* p = (const float4*)(imgf + (size_t)i0 * 2048 + d0);
        float4 u0 = p[0], u1 = p[1];
        v[0] += w0 * u0.x; v[1] += w0 * u0.y; v[2] += w0 * u0.z; v[3] += w0 * u0.w;
        v[4] += w0 * u1.x; v[5] += w0 * u1.y; v[6] += w0 * u1.z; v[7] += w0 * u1.w;
      }
      if (i1 >= 0) {
        const float4* p = (const float4*)(imgf + (size_t)i1 * 2048 + d0);
        float4 u0 = p[0], u1 = p[1];
        v[0] += w1 * u0.x; v[1] += w1 * u0.y; v[2] += w1 * u0.z; v[3] += w1 * u0.w;
        v[4] += w1 * u1.x; v[5] += w1 * u1.y; v[6] += w1 * u1.z; v[7] += w1 * u1.w;
      }
      if (i2 >= 0) {
        const float4* p = (const float4*)(imgf + (size_t)i2 * 2048 + d0);
        float4 u0 = p[0], u1 = p[1];
        v[0] += w2 * u0.x; v[1] += w2 * u0.y; v[2] += w2 * u0.z; v[3] += w2 * u0.w;
        v[4] += w2 * u1.x; v[5] += w2 * u1.y; v[6] += w2 * u1.z; v[7] += w2 * u1.w;
      }
#pragma unroll
      for (int q = 0; q < 8; ++q) v[q] += bias;
    } else if (d0 == 2048) {
      if (i0 >= 0) { float4 u = *(const float4*)(bbox + (size_t)i0 * 4);
        v[0] += w0 * u.x; v[1] += w0 * u.y; v[2] += w0 * u.z; v[3] += w0 * u.w; }
      if (i1 >= 0) { float4 u = *(const float4*)(bbox + (size_t)i1 * 4);
        v[0] += w1 * u.x; v[1] += w1 * u.y; v[2] += w1 * u.z; v[3] += w1 * u.w; }
      if (i2 >= 0) { float4 u = *(const float4*)(bbox + (size_t)i2 * 4);
        v[0] += w2 * u.x; v[1] += w2 * u.y; v[2] += w2 * u.z; v[3] += w2 * u.w; }
      v[0] += bias; v[1] += bias; v[2] += bias; v[3] += bias;
    }
    unsigned short o[8] __attribute__((aligned(16)));
#pragma unroll
    for (int q = 0; q < 8; ++q) o[q] = f2bf(v[q]);
    *(uint4*)(xbf + (size_t)r * KP + d0) = *(const uint4*)o;
  }
}

// ---------------------------------------------------------------------------
// KC: support = x_bf16 @ gcwT^T -> supportT[b][o][c pad 128] bf16.
// 128x128 tile, BK=64. Software pipeline: global->VGPR prefetch of tile k+1
// DURING tile k's MFMA phase; ds_write after the barrier. This is R3's
// structure, fixed: __launch_bounds__(256, 1) lets the allocator keep the
// 32-VGPR prefetch live (~160-200 VGPRs) WITHOUT scratch spill (R3: bare
// launch_bounds -> 84 VGPR + 507 MB scratch traffic).
// ---------------------------------------------------------------------------
__global__ __launch_bounds__(256, 1) void k_gemm1(const unsigned short* __restrict__ A,
                                                  const unsigned short* __restrict__ Bt,
                                                  unsigned short* __restrict__ ST) {
  __shared__ unsigned short shbuf[128 * 132] __attribute__((aligned(16)));  // 33.8 KB
  unsigned short* Asm = shbuf;          // staging: 8192 ushorts
  unsigned short* Bsm = shbuf + 8192;   //          8192 ushorts
  const int tid  = threadIdx.x;
  const int lane = tid & 63;
  const int w    = tid >> 6;
  // XCD swizzle: consecutive v round-robin over XCDs; each XCD owns 2 n-cols.
  const int v    = blockIdx.y * gridDim.x + blockIdx.x;  // 0..799
  const int ncol = (v & 7) * 2 + ((v >> 3) & 1);
  const int mrow = v >> 4;
  const int m0   = mrow * 128;
  const int n0   = ncol * 128;
  const int wm   = (w & 1) * 64;
  const int wn   = (w >> 1) * 64;
  const int srow = lane >> 3;                      // row within 8-row chunk (== m&7)
  const int gk   = (((lane & 7) - srow) & 7) * 8;  // swizzle-inverse k start
  const int quad = lane >> 4;
  const int lrow = lane & 15;
  const int rot  = (lane & 7) * 8;

  size_t aoff[4], boff[4];
  int ldsoff[4];
#pragma unroll
  for (int t = 0; t < 4; ++t) {
    const int chunk = t * 4 + w;
    const int row = chunk * 8 + srow;
    aoff[t] = (size_t)(m0 + row) * KP + gk;
    boff[t] = (size_t)(n0 + row) * KP + gk;
    ldsoff[t] = chunk * 512 + lane * 8;
  }

  floatx4 acc[4][4] = {};

  // prologue: stage tile 0 via async16
#pragma unroll
  for (int t = 0; t < 4; ++t) {
    const int chunk = t * 4 + w;
    async16(A  + aoff[t], &Asm[chunk * 512]);
    async16(Bt + boff[t], &Bsm[chunk * 512]);
  }
  __syncthreads();

  for (int kb = 0; kb < KP / 64; ++kb) {
    const bool more = (kb + 1) < (KP / 64);
    uint4 pa[4], pb[4];
    if (more) {
      const int knext = (kb + 1) * 64;
#pragma unroll
      for (int t = 0; t < 4; ++t) {
        pa[t] = *(const uint4*)(A  + aoff[t] + knext);
        pb[t] = *(const uint4*)(Bt + boff[t] + knext);
      }
    }
    // compute on tile kb while prefetch loads are in flight
#pragma unroll
    for (int kp = 0; kp < 2; ++kp) {
      const int koff = (kp * 32 + quad * 8 + rot) & 63;
      short8 af[4], bfr[4];
#pragma unroll
      for (int i = 0; i < 4; ++i)
        af[i]  = *(const short8*)&Asm[(wm + i * 16 + lrow) * 64 + koff];
#pragma unroll
      for (int j = 0; j < 4; ++j)
        bfr[j] = *(const short8*)&Bsm[(wn + j * 16 + lrow) * 64 + koff];
#pragma unroll
      for (int i = 0; i < 4; ++i)
#pragma unroll
        for (int j = 0; j < 4; ++j)
          acc[i][j] = __builtin_amdgcn_mfma_f32_16x16x32_bf16(af[i], bfr[j], acc[i][j], 0, 0, 0);
    }
    __syncthreads();  // LDS reads done; vmcnt drain overlapped by MFMA phase
    if (more) {
#pragma unroll
      for (int t = 0; t < 4; ++t) {
        *(uint4*)&Asm[ldsoff[t]] = pa[t];
        *(uint4*)&Bsm[ldsoff[t]] = pb[t];
      }
      __syncthreads();  // writes visible
    }
  }

  // epilogue: acc(row=m_local, col=o_local) -> LDS T[o][m] (stride 132), then
  // coalesced uint stores into ST[b][n0+o][c] (c,c+1 never straddle b: m0 even).
#pragma unroll
  for (int j = 0; j < 4; ++j) {
    const int ol = wn + j * 16 + lrow;
#pragma unroll
    for (int i = 0; i < 4; ++i) {
#pragma unroll
      for (int rr = 0; rr < 4; ++rr) {
        const int ml = wm + i * 16 + quad * 4 + rr;
        shbuf[ol * 132 + ml] = f2bf(acc[i][j][rr]);
      }
    }
  }
  __syncthreads();
#pragma unroll
  for (int it = 0; it < 32; ++it) {
    const int idx = it * 256 + tid;
    const int o = idx >> 6;          // 0..127
    const int cp = idx & 63;         // c-pair
    const int m = 2 * cp;
    const int r = m0 + m;
    const int b = r / 100;           // magic-mul
    const int c = r - b * 100;       // even; (c,c+1) same b
    const unsigned int val = *(const unsigned int*)&shbuf[o * 132 + m];
    *(unsigned int*)&ST[((size_t)b * NOUT + n0 + o) * 128 + c] = val;
  }
}

// ---------------------------------------------------------------------------
// KD: out[b,o] = sum_c g[b,c]*lrelu( sum_n (X[c,n]+adj[b,c,n]) * S[b,n,o] + gc_b[o] )
// bf16 MFMA, S^T staged via async16 from supportT (0-conflict swizzle).
// ---------------------------------------------------------------------------
__global__ __launch_bounds__(256) void k_gemm2(const float* __restrict__ X,
                                               const float* __restrict__ adj,
                                               const unsigned short* __restrict__ ST,
                                               const float* __restrict__ gf,
                                               const float* __restrict__ gcb,
                                               float* __restrict__ outp) {
  __shared__ unsigned short A2s[128 * 64] __attribute__((aligned(16)));
  __shared__ unsigned short Ssm[128 * 64] __attribute__((aligned(16)));
  __shared__ float gsm[128];
  __shared__ float red[128 * 9];
  const int tid = threadIdx.x;
  const int o0  = blockIdx.x * 128;
  const int b   = blockIdx.y;
  if (tid < 128) gsm[tid] = (tid < CC) ? gf[b * CC + tid] : 0.f;

  const int lane = tid & 63;
  const int w    = tid >> 6;
  const int srow = lane >> 3;
  const int gk   = (((lane & 7) - srow) & 7) * 8;
  const int quad = lane >> 4;
  const int lrow = lane & 15;
  const int rot  = (lane & 7) * 8;
  const int wm   = (w & 1) * 64;
  const int wn   = (w >> 1) * 64;

  floatx4 acc[4][4] = {};

  for (int kb = 0; kb < 2; ++kb) {
    const int k0 = kb * 64;
    __syncthreads();  // protect LDS reuse across kb
#pragma unroll
    for (int t = 0; t < 4; ++t) {
      const int chunk = t * 4 + w;
      const int orow = chunk * 8 + srow;
      async16(ST + ((size_t)b * NOUT + o0 + orow) * 128 + k0 + gk, &Ssm[chunk * 512]);
    }
    // A2 staging: A2[c][n] = X[c][n]+adj[b][c][n], bf16 x4, same swizzle
    {
      const int ngrp = tid & 15;
      const int cb   = tid >> 4;
      const int n    = k0 + ngrp * 4;
#pragma unroll
      for (int it = 0; it < 8; ++it) {
        const int c = it * 16 + cb;
        unsigned short pk[4] __attribute__((aligned(8))) = {0, 0, 0, 0};
        if (c < CC && n < CC) {
          const float4 a4 = *(const float4*)(adj + (size_t)b * (CC * CC) + c * CC + n);
          const float4 x4 = *(const float4*)(X + c * CC + n);
          pk[0] = f2bf(a4.x + x4.x); pk[1] = f2bf(a4.y + x4.y);
          pk[2] = f2bf(a4.z + x4.z); pk[3] = f2bf(a4.w + x4.w);
        }
        *(uint2*)&A2s[c * 64 + ((ngrp * 4 + 8 * (c & 7)) & 63)] = *(const uint2*)pk;
      }
    }
    __syncthreads();
#pragma unroll
    for (int kp = 0; kp < 2; ++kp) {
      const int koff = (kp * 32 + quad * 8 + rot) & 63;
      short8 af[4], bfr[4];
#pragma unroll
      for (int i = 0; i < 4; ++i)
        af[i]  = *(const short8*)&A2s[(wm + i * 16 + lrow) * 64 + koff];
#pragma unroll
      for (int j = 0; j < 4; ++j)
        bfr[j] = *(const short8*)&Ssm[(wn + j * 16 + lrow) * 64 + koff];
#pragma unroll
      for (int i = 0; i < 4; ++i)
#pragma unroll
        for (int j = 0; j < 4; ++j)
          acc[i][j] = __builtin_amdgcn_mfma_f32_16x16x32_bf16(af[i], bfr[j], acc[i][j], 0, 0, 0);
    }
  }
  __syncthreads();

  const int slot = (w & 1) * 4 + quad;
#pragma unroll
  for (int j = 0; j < 4; ++j) {
    const int ol = wn + j * 16 + lrow;
    const float bias = gcb[o0 + ol];
    float s = 0.f;
#pragma unroll
    for (int i = 0; i < 4; ++i) {
#pragma unroll
      for (int rr = 0; rr < 4; ++rr) {
        const int c = wm + i * 16 + quad * 4 + rr;
        float t = acc[i][j][rr] + bias;
        t = (t > 0.f) ? t : 0.01f * t;
        s += gsm[c] * t;   // gsm[c]=0 masks c>=100 pad rows
      }
    }
    red[ol * 9 + slot] = s;
  }
  __syncthreads();
  if (tid < 128) {
    float s = 0.f;
#pragma unroll
    for (int t = 0; t < 8; ++t) s += red[tid * 9 + t];
    outp[(size_t)b * NOUT + o0 + tid] = s;
  }
}

// ---------------------------------------------------------------------------
extern "C" void kernel_launch(void* const* d_in, const int* in_sizes, int n_in,
                              void* d_out, int out_size, void* d_ws, size_t ws_size,
                              hipStream_t stream) {
  const float* imgf   = (const float*)d_in[0];
  const float* bbox   = (const float*)d_in[1];
  const float* gfeat  = (const float*)d_in[2];
  const float* adj    = (const float*)d_in[3];
  const float* X      = (const float*)d_in[4];
  const float* lw     = (const float*)d_in[5];
  const float* lb     = (const float*)d_in[6];
  const float* gcw    = (const float*)d_in[7];
  const float* gcb    = (const float*)d_in[8];
  const int*   labels = (const int*)d_in[9];

  char* ws = (char*)d_ws;
  // ws layout (~69.2 MB total; ST must NOT overlay xbf -- gemm1 reads xbf
  // while writing ST):
  //   [0, 27,033,600)             xbf
  //   [27,033,600, 35,684,352)    gcwT
  //   [35,684,352, 69,238,784)    supportT [64][2048][128] bf16
  unsigned short* xbf      = (unsigned short*)(ws);
  unsigned short* gcwT     = (unsigned short*)(ws + 27033600);
  unsigned short* supportT = (unsigned short*)(ws + 35684352);
  float*          outp     = (float*)d_out;

  k_prep<<<dim3(4224 + 6400), dim3(256), 0, stream>>>(gcw, gcwT, imgf, bbox, lw, lb, labels, xbf);
  k_gemm1<<<dim3(16, 50), dim3(256), 0, stream>>>(xbf, gcwT, supportT);
  k_gemm2<<<dim3(NOUT / 128, BB), dim3(256), 0, stream>>>(X, adj, supportT, gfeat, gcb, outp);
}

// Round 6
// 298.129 us; speedup vs baseline: 1.6366x; 1.6366x over previous
//
#include <hip/hip_runtime.h>
#include <stdint.h>

// Problem constants
#define BB    64
#define CC    100
#define NBPER 150
#define FEAT  2052
#define KP    2112      // FEAT padded to 33*64 for BK=64 MFMA loop
#define NOUT  2048
#define MR    6400      // BB*CC rows of x / support

typedef __attribute__((ext_vector_type(8))) short   short8;
typedef __attribute__((ext_vector_type(4))) float   floatx4;

__device__ __forceinline__ unsigned short f2bf(float f) {
  unsigned int u = __float_as_uint(f);
  u += 0x7FFFu + ((u >> 16) & 1u);   // RNE
  return (unsigned short)(u >> 16);
}

// async global->LDS, 16B per lane. LDS dest is wave-uniform base; HW does base + lane*16.
__device__ __forceinline__ void async16(const void* g, void* l) {
  __builtin_amdgcn_global_load_lds((__attribute__((address_space(1))) void*)(g),
                                   (__attribute__((address_space(3))) void*)(l),
                                   16, 0, 0);
}

// ---------------------------------------------------------------------------
// K_PREP: tri-role kernel.
//   [0, 4224):     gc_w [2052][2048] fp32 -> gcwT [2048][2112] bf16 (K-major)
//   [4224, 4480):  buildx: 64 images x 4 c-groups of 25. Labels staged once,
//                  25 PARALLEL bucket scans, then 25 rows built cooperatively
//                  (R4/R5 ran 6400 blocks with a serial 150-iter scan each).
//   [4480, 4544):  A2p[b][c pad128][n pad128] bf16 = X + adj  (pre-packed so
//                  gemm2 can async16-stage it with zero VALU work)
// ---------------------------------------------------------------------------
__global__ __launch_bounds__(256) void k_prep(const float* __restrict__ gcw,
                                              unsigned short* __restrict__ gcwT,
                                              const float* __restrict__ imgf,
                                              const float* __restrict__ bbox,
                                              const float* __restrict__ lw,
                                              const float* __restrict__ lb,
                                              const int* __restrict__ labels,
                                              unsigned short* __restrict__ xbf,
                                              const float* __restrict__ X,
                                              const float* __restrict__ adj,
                                              unsigned short* __restrict__ A2p) {
  __shared__ float tile[32][33];
  __shared__ int lab[NBPER];
  __shared__ int sidx2[25][3];
  const int bx  = blockIdx.x;
  const int tid = threadIdx.x;

  if (bx < 4224) {
    // ---- transpose role ----
    const int ko = bx % 66;
    const int oo = bx / 66;
    const int tx = tid & 31, ty = tid >> 5;
#pragma unroll
    for (int i = 0; i < 4; ++i) {
      const int k = ko * 32 + ty + i * 8;
      const int o = oo * 32 + tx;
      tile[ty + i * 8][tx] = (k < FEAT) ? gcw[(size_t)k * NOUT + o] : 0.f;
    }
    __syncthreads();
#pragma unroll
    for (int i = 0; i < 4; ++i) {
      const int o = oo * 32 + ty + i * 8;
      const int k = ko * 32 + tx;
      gcwT[(size_t)o * KP + k] = f2bf(tile[tx][ty + i * 8]);
    }
    return;
  }

  if (bx < 4480) {
    // ---- buildx role ----
    const int r2 = bx - 4224;        // 0..255
    const int b  = r2 >> 2;
    const int cg = r2 & 3;           // c in [cg*25, cg*25+25)
    if (tid < NBPER) lab[tid] = labels[b * NBPER + tid];
    __syncthreads();
    if (tid < 25) {
      const int c = cg * 25 + tid;
      int cnt = 0, o0 = -1, o1 = -1, o2 = -1;
      for (int i = 0; i < NBPER; ++i) {
        if (lab[i] == c + 1) {
          if (cnt == 0) o0 = b * NBPER + i;
          else if (cnt == 1) o1 = b * NBPER + i;
          else if (cnt == 2) o2 = b * NBPER + i;
          ++cnt;
        }
      }
      sidx2[tid][0] = o0; sidx2[tid][1] = o1; sidx2[tid][2] = o2;
    }
    __syncthreads();
    const float w0 = lw[0], w1 = lw[1], w2 = lw[2], bias = lb[0];
    for (int cl = 0; cl < 25; ++cl) {
      const int c = cg * 25 + cl;
      const int r = b * CC + c;
      const int i0 = sidx2[cl][0], i1 = sidx2[cl][1], i2 = sidx2[cl][2];
      for (int s = tid; s < KP / 8; s += 256) {
        const int d0 = s * 8;
        float v[8];
#pragma unroll
        for (int q = 0; q < 8; ++q) v[q] = 0.f;
        if (d0 < 2048) {
          if (i0 >= 0) {
            const float4* p = (const float4*)(imgf + (size_t)i0 * 2048 + d0);
            float4 u0 = p[0], u1 = p[1];
            v[0] += w0 * u0.x; v[1] += w0 * u0.y; v[2] += w0 * u0.z; v[3] += w0 * u0.w;
            v[4] += w0 * u1.x; v[5] += w0 * u1.y; v[6] += w0 * u1.z; v[7] += w0 * u1.w;
          }
          if (i1 >= 0) {
            const float4* p = (const float4*)(imgf + (size_t)i1 * 2048 + d0);
            float4 u0 = p[0], u1 = p[1];
            v[0] += w1 * u0.x; v[1] += w1 * u0.y; v[2] += w1 * u0.z; v[3] += w1 * u0.w;
            v[4] += w1 * u1.x; v[5] += w1 * u1.y; v[6] += w1 * u1.z; v[7] += w1 * u1.w;
          }
          if (i2 >= 0) {
            const float4* p = (const float4*)(imgf + (size_t)i2 * 2048 + d0);
            float4 u0 = p[0], u1 = p[1];
            v[0] += w2 * u0.x; v[1] += w2 * u0.y; v[2] += w2 * u0.z; v[3] += w2 * u0.w;
            v[4] += w2 * u1.x; v[5] += w2 * u1.y; v[6] += w2 * u1.z; v[7] += w2 * u1.w;
          }
#pragma unroll
          for (int q = 0; q < 8; ++q) v[q] += bias;
        } else if (d0 == 2048) {
          if (i0 >= 0) { float4 u = *(const float4*)(bbox + (size_t)i0 * 4);
            v[0] += w0 * u.x; v[1] += w0 * u.y; v[2] += w0 * u.z; v[3] += w0 * u.w; }
          if (i1 >= 0) { float4 u = *(const float4*)(bbox + (size_t)i1 * 4);
            v[0] += w1 * u.x; v[1] += w1 * u.y; v[2] += w1 * u.z; v[3] += w1 * u.w; }
          if (i2 >= 0) { float4 u = *(const float4*)(bbox + (size_t)i2 * 4);
            v[0] += w2 * u.x; v[1] += w2 * u.y; v[2] += w2 * u.z; v[3] += w2 * u.w; }
          v[0] += bias; v[1] += bias; v[2] += bias; v[3] += bias;
        }
        unsigned short o[8] __attribute__((aligned(16)));
#pragma unroll
        for (int q = 0; q < 8; ++q) o[q] = f2bf(v[q]);
        *(uint4*)(xbf + (size_t)r * KP + d0) = *(const uint4*)o;
      }
    }
    return;
  }

  // ---- A2p role ----
  {
    const int b = bx - 4480;
#pragma unroll
    for (int it = 0; it < 16; ++it) {
      const int idx = it * 256 + tid;
      const int c = idx >> 5, ng = idx & 31;
      const int n = ng * 4;
      unsigned short pk[4] __attribute__((aligned(8))) = {0, 0, 0, 0};
      if (c < CC && n < CC) {   // n multiple of 4 -> n+3 <= 99
        const float4 a4 = *(const float4*)(adj + (size_t)b * (CC * CC) + c * CC + n);
        const float4 x4 = *(const float4*)(X + c * CC + n);
        pk[0] = f2bf(a4.x + x4.x); pk[1] = f2bf(a4.y + x4.y);
        pk[2] = f2bf(a4.z + x4.z); pk[3] = f2bf(a4.w + x4.w);
      }
      *(uint2*)&A2p[((size_t)b * 128 + c) * 128 + n] = *(const uint2*)pk;
    }
  }
}

// ---------------------------------------------------------------------------
// KC: support = x_bf16 @ gcwT^T -> supportT[b][o][c pad 128] bf16.
// EXACT R4 structure: async16 staging, 2-barrier K-loop (NO VGPR prefetch --
// spilled in R3 and R5 regardless of launch_bounds), XCD swizzle,
// LDS-transpose epilogue.
// ---------------------------------------------------------------------------
__global__ __launch_bounds__(256) void k_gemm1(const unsigned short* __restrict__ A,
                                               const unsigned short* __restrict__ Bt,
                                               unsigned short* __restrict__ ST) {
  __shared__ unsigned short shbuf[128 * 132] __attribute__((aligned(16)));  // 33.8 KB
  unsigned short* Asm = shbuf;          // staging: 8192 ushorts
  unsigned short* Bsm = shbuf + 8192;   //          8192 ushorts
  const int tid  = threadIdx.x;
  const int lane = tid & 63;
  const int w    = tid >> 6;
  const int v    = blockIdx.y * gridDim.x + blockIdx.x;  // 0..799
  const int ncol = (v & 7) * 2 + ((v >> 3) & 1);
  const int mrow = v >> 4;
  const int m0   = mrow * 128;
  const int n0   = ncol * 128;
  const int wm   = (w & 1) * 64;
  const int wn   = (w >> 1) * 64;
  const int srow = lane >> 3;                      // row within 8-row chunk (== m&7)
  const int gk   = (((lane & 7) - srow) & 7) * 8;  // swizzle-inverse k start
  const int quad = lane >> 4;
  const int lrow = lane & 15;
  const int rot  = (lane & 7) * 8;

  floatx4 acc[4][4] = {};

  for (int kb = 0; kb < KP / 64; ++kb) {
    const int k0 = kb * 64;
#pragma unroll
    for (int t = 0; t < 4; ++t) {
      const int chunk = t * 4 + w;
      const int row = chunk * 8 + srow;
      async16(A  + (size_t)(m0 + row) * KP + (k0 + gk), &Asm[chunk * 512]);
      async16(Bt + (size_t)(n0 + row) * KP + (k0 + gk), &Bsm[chunk * 512]);
    }
    __syncthreads();  // drains vmcnt + barrier
#pragma unroll
    for (int kp = 0; kp < 2; ++kp) {
      const int koff = (kp * 32 + quad * 8 + rot) & 63;
      short8 af[4], bfr[4];
#pragma unroll
      for (int i = 0; i < 4; ++i)
        af[i]  = *(const short8*)&Asm[(wm + i * 16 + lrow) * 64 + koff];
#pragma unroll
      for (int j = 0; j < 4; ++j)
        bfr[j] = *(const short8*)&Bsm[(wn + j * 16 + lrow) * 64 + koff];
#pragma unroll
      for (int i = 0; i < 4; ++i)
#pragma unroll
        for (int j = 0; j < 4; ++j)
          acc[i][j] = __builtin_amdgcn_mfma_f32_16x16x32_bf16(af[i], bfr[j], acc[i][j], 0, 0, 0);
    }
    __syncthreads();
  }

  // epilogue: acc(row=m_local, col=o_local) -> LDS T[o][m] (stride 132), then
  // coalesced uint stores into ST[b][n0+o][c] (c,c+1 never straddle b: m0 even).
#pragma unroll
  for (int j = 0; j < 4; ++j) {
    const int ol = wn + j * 16 + lrow;
#pragma unroll
    for (int i = 0; i < 4; ++i) {
#pragma unroll
      for (int rr = 0; rr < 4; ++rr) {
        const int ml = wm + i * 16 + quad * 4 + rr;
        shbuf[ol * 132 + ml] = f2bf(acc[i][j][rr]);
      }
    }
  }
  __syncthreads();
#pragma unroll
  for (int it = 0; it < 32; ++it) {
    const int idx = it * 256 + tid;
    const int o = idx >> 6;          // 0..127
    const int cp = idx & 63;         // c-pair
    const int m = 2 * cp;
    const int r = m0 + m;
    const int b = r / 100;           // magic-mul
    const int c = r - b * 100;       // even; (c,c+1) same b
    const unsigned int val = *(const unsigned int*)&shbuf[o * 132 + m];
    *(unsigned int*)&ST[((size_t)b * NOUT + n0 + o) * 128 + c] = val;
  }
}

// ---------------------------------------------------------------------------
// KD: out[b,o] = sum_c g[b,c]*lrelu( sum_n A2[c,n] * S[b,n,o] + gc_b[o] )
// bf16 MFMA; BOTH operands async16-staged from pre-packed A2p / supportT
// (zero VALU pack work in the hot kernel).
// ---------------------------------------------------------------------------
__global__ __launch_bounds__(256) void k_gemm2(const unsigned short* __restrict__ A2p,
                                               const unsigned short* __restrict__ ST,
                                               const float* __restrict__ gf,
                                               const float* __restrict__ gcb,
                                               float* __restrict__ outp) {
  __shared__ unsigned short A2s[128 * 64] __attribute__((aligned(16)));
  __shared__ unsigned short Ssm[128 * 64] __attribute__((aligned(16)));
  __shared__ float gsm[128];
  __shared__ float red[128 * 9];
  const int tid = threadIdx.x;
  const int o0  = blockIdx.x * 128;
  const int b   = blockIdx.y;
  if (tid < 128) gsm[tid] = (tid < CC) ? gf[b * CC + tid] : 0.f;

  const int lane = tid & 63;
  const int w    = tid >> 6;
  const int srow = lane >> 3;
  const int gk   = (((lane & 7) - srow) & 7) * 8;
  const int quad = lane >> 4;
  const int lrow = lane & 15;
  const int rot  = (lane & 7) * 8;
  const int wm   = (w & 1) * 64;
  const int wn   = (w >> 1) * 64;

  floatx4 acc[4][4] = {};

  for (int kb = 0; kb < 2; ++kb) {
    const int k0 = kb * 64;
    __syncthreads();  // protect LDS reuse across kb (and gsm ordering)
#pragma unroll
    for (int t = 0; t < 4; ++t) {
      const int chunk = t * 4 + w;
      const int row = chunk * 8 + srow;
      async16(A2p + ((size_t)b * 128 + row) * 128 + k0 + gk, &A2s[chunk * 512]);
      async16(ST + ((size_t)b * NOUT + o0 + row) * 128 + k0 + gk, &Ssm[chunk * 512]);
    }
    __syncthreads();
#pragma unroll
    for (int kp = 0; kp < 2; ++kp) {
      const int koff = (kp * 32 + quad * 8 + rot) & 63;
      short8 af[4], bfr[4];
#pragma unroll
      for (int i = 0; i < 4; ++i)
        af[i]  = *(const short8*)&A2s[(wm + i * 16 + lrow) * 64 + koff];
#pragma unroll
      for (int j = 0; j < 4; ++j)
        bfr[j] = *(const short8*)&Ssm[(wn + j * 16 + lrow) * 64 + koff];
#pragma unroll
      for (int i = 0; i < 4; ++i)
#pragma unroll
        for (int j = 0; j < 4; ++j)
          acc[i][j] = __builtin_amdgcn_mfma_f32_16x16x32_bf16(af[i], bfr[j], acc[i][j], 0, 0, 0);
    }
  }
  __syncthreads();

  // epilogue: out_o = sum_c g[c]*lrelu(T[c][o]+bias[o])
  const int slot = (w & 1) * 4 + quad;
#pragma unroll
  for (int j = 0; j < 4; ++j) {
    const int ol = wn + j * 16 + lrow;
    const float bias = gcb[o0 + ol];
    float s = 0.f;
#pragma unroll
    for (int i = 0; i < 4; ++i) {
#pragma unroll
      for (int rr = 0; rr < 4; ++rr) {
        const int c = wm + i * 16 + quad * 4 + rr;
        float t = acc[i][j][rr] + bias;
        t = (t > 0.f) ? t : 0.01f * t;
        s += gsm[c] * t;   // gsm[c]=0 masks c>=100 pad rows
      }
    }
    red[ol * 9 + slot] = s;
  }
  __syncthreads();
  if (tid < 128) {
    float s = 0.f;
#pragma unroll
    for (int t = 0; t < 8; ++t) s += red[tid * 9 + t];
    outp[(size_t)b * NOUT + o0 + tid] = s;
  }
}

// ---------------------------------------------------------------------------
extern "C" void kernel_launch(void* const* d_in, const int* in_sizes, int n_in,
                              void* d_out, int out_size, void* d_ws, size_t ws_size,
                              hipStream_t stream) {
  const float* imgf   = (const float*)d_in[0];
  const float* bbox   = (const float*)d_in[1];
  const float* gfeat  = (const float*)d_in[2];
  const float* adj    = (const float*)d_in[3];
  const float* X      = (const float*)d_in[4];
  const float* lw     = (const float*)d_in[5];
  const float* lb     = (const float*)d_in[6];
  const float* gcw    = (const float*)d_in[7];
  const float* gcb    = (const float*)d_in[8];
  const int*   labels = (const int*)d_in[9];

  char* ws = (char*)d_ws;
  // ws layout (~71.3 MB; ST must NOT overlay xbf -- gemm1 reads xbf while
  // writing ST):
  //   [0, 27,033,600)             xbf
  //   [27,033,600, 35,684,352)    gcwT
  //   [35,684,352, 69,238,784)    supportT [64][2048][128] bf16
  //   [69,238,784, 71,335,936)    A2p      [64][128][128] bf16
  unsigned short* xbf      = (unsigned short*)(ws);
  unsigned short* gcwT     = (unsigned short*)(ws + 27033600);
  unsigned short* supportT = (unsigned short*)(ws + 35684352);
  unsigned short* A2p      = (unsigned short*)(ws + 69238784);
  float*          outp     = (float*)d_out;

  k_prep<<<dim3(4544), dim3(256), 0, stream>>>(gcw, gcwT, imgf, bbox, lw, lb,
                                               labels, xbf, X, adj, A2p);
  k_gemm1<<<dim3(16, 50), dim3(256), 0, stream>>>(xbf, gcwT, supportT);
  k_gemm2<<<dim3(NOUT / 128, BB), dim3(256), 0, stream>>>(A2p, supportT, gfeat, gcb, outp);
}

// Round 7
// 270.024 us; speedup vs baseline: 1.8070x; 1.1041x over previous
//
#include <hip/hip_runtime.h>
#include <stdint.h>

// Problem constants
#define BB    64
#define CC    100
#define NBPER 150
#define FEAT  2052
#define KP    2112      // FEAT padded to 33*64 for BK=64 MFMA loop
#define NOUT  2048
#define MR    6400      // BB*CC rows of x / support

typedef __attribute__((ext_vector_type(8))) short   short8;
typedef __attribute__((ext_vector_type(4))) float   floatx4;

__device__ __forceinline__ unsigned short f2bf(float f) {
  unsigned int u = __float_as_uint(f);
  u += 0x7FFFu + ((u >> 16) & 1u);   // RNE
  return (unsigned short)(u >> 16);
}

// async global->LDS, 16B per lane. LDS dest is wave-uniform base; HW does base + lane*16.
__device__ __forceinline__ void async16(const void* g, void* l) {
  __builtin_amdgcn_global_load_lds((__attribute__((address_space(1))) void*)(g),
                                   (__attribute__((address_space(3))) void*)(l),
                                   16, 0, 0);
}

// ---------------------------------------------------------------------------
// K_PREP v2: tri-role, heavy blocks FIRST, parallelism/MLP fixed (R6 version
// ran 102us at 11% occupancy / VGPR 16: serial 25-row builds + tiny blocks).
//   [0, 512):      buildx: (image b, k-slice of 33 chunks). Labels staged
//                  once, 100 PARALLEL bucket scans, flat row*chunk loop
//                  (13 independent gather iters/thread).
//   [512, 1568):   gc_w -> gcwT bf16 transpose, 64x64 tiles (16 independent
//                  coalesced loads/thread).
//   [1568, 1632):  A2p[b][c pad128][n pad128] bf16 = X + adj (zero-padded)
// ---------------------------------------------------------------------------
__global__ __launch_bounds__(256) void k_prep(const float* __restrict__ gcw,
                                              unsigned short* __restrict__ gcwT,
                                              const float* __restrict__ imgf,
                                              const float* __restrict__ bbox,
                                              const float* __restrict__ lw,
                                              const float* __restrict__ lb,
                                              const int* __restrict__ labels,
                                              unsigned short* __restrict__ xbf,
                                              const float* __restrict__ X,
                                              const float* __restrict__ adj,
                                              unsigned short* __restrict__ A2p) {
  __shared__ float smf[64 * 65];   // 16.6 KB; aliased by buildx's lab/sidx
  const int bx  = blockIdx.x;
  const int tid = threadIdx.x;

  if (bx < 512) {
    // ---- buildx role ----
    int* lab  = (int*)smf;         // [150]
    int* sidx = lab + NBPER;       // [100][3]
    const int b  = bx >> 3;
    const int sl = bx & 7;         // chunk cols [sl*33, sl*33+33)
    if (tid < NBPER) lab[tid] = labels[b * NBPER + tid];
    __syncthreads();
    if (tid < CC) {                // parallel stable scan, one thread per category
      int o0 = -1, o1 = -1, o2 = -1, cnt = 0;
      for (int i = 0; i < NBPER; ++i) {
        if (lab[i] == tid + 1) {
          if (cnt == 0) o0 = b * NBPER + i;
          else if (cnt == 1) o1 = b * NBPER + i;
          else if (cnt == 2) o2 = b * NBPER + i;
          ++cnt;
        }
      }
      sidx[tid * 3] = o0; sidx[tid * 3 + 1] = o1; sidx[tid * 3 + 2] = o2;
    }
    __syncthreads();
    const float w0 = lw[0], w1 = lw[1], w2 = lw[2], bias = lb[0];
    for (int idx = tid; idx < CC * 33; idx += 256) {
      const int cl  = idx / 33;                 // category (magic-div)
      const int col = sl * 33 + (idx - cl * 33);  // chunk col 0..263
      const int d0  = col * 8;
      const int r   = b * CC + cl;
      const int i0 = sidx[cl * 3], i1 = sidx[cl * 3 + 1], i2 = sidx[cl * 3 + 2];
      float v[8];
#pragma unroll
      for (int q = 0; q < 8; ++q) v[q] = 0.f;
      if (d0 < 2048) {
        // issue all loads first (MLP), then FMA
        float4 a0, a1, b0, b1, c0, c1;
        if (i0 >= 0) { const float4* p = (const float4*)(imgf + (size_t)i0 * 2048 + d0); a0 = p[0]; a1 = p[1]; }
        if (i1 >= 0) { const float4* p = (const float4*)(imgf + (size_t)i1 * 2048 + d0); b0 = p[0]; b1 = p[1]; }
        if (i2 >= 0) { const float4* p = (const float4*)(imgf + (size_t)i2 * 2048 + d0); c0 = p[0]; c1 = p[1]; }
        if (i0 >= 0) {
          v[0] += w0 * a0.x; v[1] += w0 * a0.y; v[2] += w0 * a0.z; v[3] += w0 * a0.w;
          v[4] += w0 * a1.x; v[5] += w0 * a1.y; v[6] += w0 * a1.z; v[7] += w0 * a1.w;
        }
        if (i1 >= 0) {
          v[0] += w1 * b0.x; v[1] += w1 * b0.y; v[2] += w1 * b0.z; v[3] += w1 * b0.w;
          v[4] += w1 * b1.x; v[5] += w1 * b1.y; v[6] += w1 * b1.z; v[7] += w1 * b1.w;
        }
        if (i2 >= 0) {
          v[0] += w2 * c0.x; v[1] += w2 * c0.y; v[2] += w2 * c0.z; v[3] += w2 * c0.w;
          v[4] += w2 * c1.x; v[5] += w2 * c1.y; v[6] += w2 * c1.z; v[7] += w2 * c1.w;
        }
#pragma unroll
        for (int q = 0; q < 8; ++q) v[q] += bias;
      } else if (d0 == 2048) {
        if (i0 >= 0) { float4 u = *(const float4*)(bbox + (size_t)i0 * 4);
          v[0] += w0 * u.x; v[1] += w0 * u.y; v[2] += w0 * u.z; v[3] += w0 * u.w; }
        if (i1 >= 0) { float4 u = *(const float4*)(bbox + (size_t)i1 * 4);
          v[0] += w1 * u.x; v[1] += w1 * u.y; v[2] += w1 * u.z; v[3] += w1 * u.w; }
        if (i2 >= 0) { float4 u = *(const float4*)(bbox + (size_t)i2 * 4);
          v[0] += w2 * u.x; v[1] += w2 * u.y; v[2] += w2 * u.z; v[3] += w2 * u.w; }
        v[0] += bias; v[1] += bias; v[2] += bias; v[3] += bias;
      }  // d0 > 2048: zeros (gcwT is also zero there, but keep it clean)
      unsigned short o[8] __attribute__((aligned(16)));
#pragma unroll
      for (int q = 0; q < 8; ++q) o[q] = f2bf(v[q]);
      *(uint4*)(xbf + (size_t)r * KP + d0) = *(const uint4*)o;
    }
    return;
  }

  if (bx < 1568) {
    // ---- transpose role: 64x64 tile ----
    const int t  = bx - 512;       // 0..1055
    const int ko = t % 33;
    const int oo = t / 33;
    const int cc = tid & 63, r0 = tid >> 6;
#pragma unroll
    for (int i = 0; i < 16; ++i) {
      const int r = r0 * 16 + i;
      const int k = ko * 64 + r;
      smf[r * 65 + cc] = (k < FEAT) ? gcw[(size_t)k * NOUT + oo * 64 + cc] : 0.f;
    }
    __syncthreads();
    const int ol = tid >> 2;       // 0..63
    const int kq = tid & 3;        // covers 16 k's
    unsigned short buf[16] __attribute__((aligned(16)));
#pragma unroll
    for (int j = 0; j < 16; ++j) buf[j] = f2bf(smf[(kq * 16 + j) * 65 + ol]);
    const size_t base = (size_t)(oo * 64 + ol) * KP + ko * 64 + kq * 16;
    *(uint4*)&gcwT[base]     = *(const uint4*)&buf[0];
    *(uint4*)&gcwT[base + 8] = *(const uint4*)&buf[8];
    return;
  }

  // ---- A2p role ----
  {
    const int b = bx - 1568;
#pragma unroll
    for (int it = 0; it < 16; ++it) {
      const int idx = it * 256 + tid;
      const int c = idx >> 5, ng = idx & 31;
      const int n = ng * 4;
      unsigned short pk[4] __attribute__((aligned(8))) = {0, 0, 0, 0};
      if (c < CC && n < CC) {   // n multiple of 4 -> n+3 <= 99
        const float4 a4 = *(const float4*)(adj + (size_t)b * (CC * CC) + c * CC + n);
        const float4 x4 = *(const float4*)(X + c * CC + n);
        pk[0] = f2bf(a4.x + x4.x); pk[1] = f2bf(a4.y + x4.y);
        pk[2] = f2bf(a4.z + x4.z); pk[3] = f2bf(a4.w + x4.w);
      }
      *(uint2*)&A2p[((size_t)b * 128 + c) * 128 + n] = *(const uint2*)pk;
    }
  }
}

// ---------------------------------------------------------------------------
// KC: support = x_bf16 @ gcwT^T -> supportT[b][o][c pad 128] bf16.
// R4-proven structure: async16 staging, 2-barrier K-loop (NO VGPR prefetch --
// spilled in R3 and R5 regardless of launch_bounds), XCD swizzle,
// LDS-transpose epilogue.
// ---------------------------------------------------------------------------
__global__ __launch_bounds__(256) void k_gemm1(const unsigned short* __restrict__ A,
                                               const unsigned short* __restrict__ Bt,
                                               unsigned short* __restrict__ ST) {
  __shared__ unsigned short shbuf[128 * 132] __attribute__((aligned(16)));  // 33.8 KB
  unsigned short* Asm = shbuf;          // staging: 8192 ushorts
  unsigned short* Bsm = shbuf + 8192;   //          8192 ushorts
  const int tid  = threadIdx.x;
  const int lane = tid & 63;
  const int w    = tid >> 6;
  const int v    = blockIdx.y * gridDim.x + blockIdx.x;  // 0..799
  const int ncol = (v & 7) * 2 + ((v >> 3) & 1);
  const int mrow = v >> 4;
  const int m0   = mrow * 128;
  const int n0   = ncol * 128;
  const int wm   = (w & 1) * 64;
  const int wn   = (w >> 1) * 64;
  const int srow = lane >> 3;                      // row within 8-row chunk (== m&7)
  const int gk   = (((lane & 7) - srow) & 7) * 8;  // swizzle-inverse k start
  const int quad = lane >> 4;
  const int lrow = lane & 15;
  const int rot  = (lane & 7) * 8;

  floatx4 acc[4][4] = {};

  for (int kb = 0; kb < KP / 64; ++kb) {
    const int k0 = kb * 64;
#pragma unroll
    for (int t = 0; t < 4; ++t) {
      const int chunk = t * 4 + w;
      const int row = chunk * 8 + srow;
      async16(A  + (size_t)(m0 + row) * KP + (k0 + gk), &Asm[chunk * 512]);
      async16(Bt + (size_t)(n0 + row) * KP + (k0 + gk), &Bsm[chunk * 512]);
    }
    __syncthreads();  // drains vmcnt + barrier
#pragma unroll
    for (int kp = 0; kp < 2; ++kp) {
      const int koff = (kp * 32 + quad * 8 + rot) & 63;
      short8 af[4], bfr[4];
#pragma unroll
      for (int i = 0; i < 4; ++i)
        af[i]  = *(const short8*)&Asm[(wm + i * 16 + lrow) * 64 + koff];
#pragma unroll
      for (int j = 0; j < 4; ++j)
        bfr[j] = *(const short8*)&Bsm[(wn + j * 16 + lrow) * 64 + koff];
#pragma unroll
      for (int i = 0; i < 4; ++i)
#pragma unroll
        for (int j = 0; j < 4; ++j)
          acc[i][j] = __builtin_amdgcn_mfma_f32_16x16x32_bf16(af[i], bfr[j], acc[i][j], 0, 0, 0);
    }
    __syncthreads();
  }

  // epilogue: acc(row=m_local, col=o_local) -> LDS T[o][m] (stride 132), then
  // coalesced uint stores into ST[b][n0+o][c] (c,c+1 never straddle b: m0 even).
#pragma unroll
  for (int j = 0; j < 4; ++j) {
    const int ol = wn + j * 16 + lrow;
#pragma unroll
    for (int i = 0; i < 4; ++i) {
#pragma unroll
      for (int rr = 0; rr < 4; ++rr) {
        const int ml = wm + i * 16 + quad * 4 + rr;
        shbuf[ol * 132 + ml] = f2bf(acc[i][j][rr]);
      }
    }
  }
  __syncthreads();
#pragma unroll
  for (int it = 0; it < 32; ++it) {
    const int idx = it * 256 + tid;
    const int o = idx >> 6;          // 0..127
    const int cp = idx & 63;         // c-pair
    const int m = 2 * cp;
    const int r = m0 + m;
    const int b = r / 100;           // magic-mul
    const int c = r - b * 100;       // even; (c,c+1) same b
    const unsigned int val = *(const unsigned int*)&shbuf[o * 132 + m];
    *(unsigned int*)&ST[((size_t)b * NOUT + n0 + o) * 128 + c] = val;
  }
}

// ---------------------------------------------------------------------------
// KD: out[b,o] = sum_c g[b,c]*lrelu( sum_n A2[c,n] * S[b,n,o] + gc_b[o] )
// bf16 MFMA; BOTH operands async16-staged from pre-packed A2p / supportT.
// ST pad c>=100 may be garbage; A2p rows are zero there so products vanish.
// ---------------------------------------------------------------------------
__global__ __launch_bounds__(256) void k_gemm2(const unsigned short* __restrict__ A2p,
                                               const unsigned short* __restrict__ ST,
                                               const float* __restrict__ gf,
                                               const float* __restrict__ gcb,
                                               float* __restrict__ outp) {
  __shared__ unsigned short A2s[128 * 64] __attribute__((aligned(16)));
  __shared__ unsigned short Ssm[128 * 64] __attribute__((aligned(16)));
  __shared__ float gsm[128];
  __shared__ float red[128 * 9];
  const int tid = threadIdx.x;
  const int o0  = blockIdx.x * 128;
  const int b   = blockIdx.y;
  if (tid < 128) gsm[tid] = (tid < CC) ? gf[b * CC + tid] : 0.f;

  const int lane = tid & 63;
  const int w    = tid >> 6;
  const int srow = lane >> 3;
  const int gk   = (((lane & 7) - srow) & 7) * 8;
  const int quad = lane >> 4;
  const int lrow = lane & 15;
  const int rot  = (lane & 7) * 8;
  const int wm   = (w & 1) * 64;
  const int wn   = (w >> 1) * 64;

  floatx4 acc[4][4] = {};

  for (int kb = 0; kb < 2; ++kb) {
    const int k0 = kb * 64;
    __syncthreads();  // protect LDS reuse across kb (and gsm ordering)
#pragma unroll
    for (int t = 0; t < 4; ++t) {
      const int chunk = t * 4 + w;
      const int row = chunk * 8 + srow;
      async16(A2p + ((size_t)b * 128 + row) * 128 + k0 + gk, &A2s[chunk * 512]);
      async16(ST + ((size_t)b * NOUT + o0 + row) * 128 + k0 + gk, &Ssm[chunk * 512]);
    }
    __syncthreads();
#pragma unroll
    for (int kp = 0; kp < 2; ++kp) {
      const int koff = (kp * 32 + quad * 8 + rot) & 63;
      short8 af[4], bfr[4];
#pragma unroll
      for (int i = 0; i < 4; ++i)
        af[i]  = *(const short8*)&A2s[(wm + i * 16 + lrow) * 64 + koff];
#pragma unroll
      for (int j = 0; j < 4; ++j)
        bfr[j] = *(const short8*)&Ssm[(wn + j * 16 + lrow) * 64 + koff];
#pragma unroll
      for (int i = 0; i < 4; ++i)
#pragma unroll
        for (int j = 0; j < 4; ++j)
          acc[i][j] = __builtin_amdgcn_mfma_f32_16x16x32_bf16(af[i], bfr[j], acc[i][j], 0, 0, 0);
    }
  }
  __syncthreads();

  // epilogue: out_o = sum_c g[c]*lrelu(T[c][o]+bias[o])
  const int slot = (w & 1) * 4 + quad;
#pragma unroll
  for (int j = 0; j < 4; ++j) {
    const int ol = wn + j * 16 + lrow;
    const float bias = gcb[o0 + ol];
    float s = 0.f;
#pragma unroll
    for (int i = 0; i < 4; ++i) {
#pragma unroll
      for (int rr = 0; rr < 4; ++rr) {
        const int c = wm + i * 16 + quad * 4 + rr;
        float t = acc[i][j][rr] + bias;
        t = (t > 0.f) ? t : 0.01f * t;
        s += gsm[c] * t;   // gsm[c]=0 masks c>=100 pad rows
      }
    }
    red[ol * 9 + slot] = s;
  }
  __syncthreads();
  if (tid < 128) {
    float s = 0.f;
#pragma unroll
    for (int t = 0; t < 8; ++t) s += red[tid * 9 + t];
    outp[(size_t)b * NOUT + o0 + tid] = s;
  }
}

// ---------------------------------------------------------------------------
extern "C" void kernel_launch(void* const* d_in, const int* in_sizes, int n_in,
                              void* d_out, int out_size, void* d_ws, size_t ws_size,
                              hipStream_t stream) {
  const float* imgf   = (const float*)d_in[0];
  const float* bbox   = (const float*)d_in[1];
  const float* gfeat  = (const float*)d_in[2];
  const float* adj    = (const float*)d_in[3];
  const float* X      = (const float*)d_in[4];
  const float* lw     = (const float*)d_in[5];
  const float* lb     = (const float*)d_in[6];
  const float* gcw    = (const float*)d_in[7];
  const float* gcb    = (const float*)d_in[8];
  const int*   labels = (const int*)d_in[9];

  char* ws = (char*)d_ws;
  // ws layout (~71.3 MB; ST must NOT overlay xbf -- gemm1 reads xbf while
  // writing ST):
  //   [0, 27,033,600)             xbf
  //   [27,033,600, 35,684,352)    gcwT
  //   [35,684,352, 69,238,784)    supportT [64][2048][128] bf16
  //   [69,238,784, 71,335,936)    A2p      [64][128][128] bf16
  unsigned short* xbf      = (unsigned short*)(ws);
  unsigned short* gcwT     = (unsigned short*)(ws + 27033600);
  unsigned short* supportT = (unsigned short*)(ws + 35684352);
  unsigned short* A2p      = (unsigned short*)(ws + 69238784);
  float*          outp     = (float*)d_out;

  k_prep<<<dim3(1632), dim3(256), 0, stream>>>(gcw, gcwT, imgf, bbox, lw, lb,
                                               labels, xbf, X, adj, A2p);
  k_gemm1<<<dim3(16, 50), dim3(256), 0, stream>>>(xbf, gcwT, supportT);
  k_gemm2<<<dim3(NOUT / 128, BB), dim3(256), 0, stream>>>(A2p, supportT, gfeat, gcb, outp);
}

// Round 8
// 268.493 us; speedup vs baseline: 1.8173x; 1.0057x over previous
//
#include <hip/hip_runtime.h>
#include <stdint.h>

// Problem constants
#define BB    64
#define CC    100
#define NBPER 150
#define FEAT  2052
#define KP    2112      // FEAT padded to 33*64 for BK=64 MFMA loop
#define NOUT  2048
#define MR    6400      // BB*CC rows of x / support

typedef __attribute__((ext_vector_type(8))) short   short8;
typedef __attribute__((ext_vector_type(4))) float   floatx4;

__device__ __forceinline__ unsigned short f2bf(float f) {
  unsigned int u = __float_as_uint(f);
  u += 0x7FFFu + ((u >> 16) & 1u);   // RNE
  return (unsigned short)(u >> 16);
}

// async global->LDS, 16B per lane. LDS dest is wave-uniform base; HW does base + lane*16.
__device__ __forceinline__ void async16(const void* g, void* l) {
  __builtin_amdgcn_global_load_lds((__attribute__((address_space(1))) void*)(g),
                                   (__attribute__((address_space(3))) void*)(l),
                                   16, 0, 0);
}

// ---------------------------------------------------------------------------
// K_PREP v3: tri-role, BRANCHLESS buildx gathers (R6/R7 versions were
// latency-serialized: `if (idx>=0)` guards let the compiler sink loads into
// branches -> VGPR_Count 16, no MLP, ~70-100us for 105 MB of traffic).
// Scan emits (index, weight) with idx=0,w=0 for absent slots -> all loads
// unconditional, 6 independent float4s in flight per task.
//   [0, 768):      buildx: (image, 22-col k-slice). 768 blocks = 3/CU.
//   [768, 1824):   gc_w -> gcwT bf16 transpose, 64x64 tiles.
//   [1824, 1888):  A2p[b][c pad128][n pad128] bf16 = X + adj (zero-padded)
// ---------------------------------------------------------------------------
__global__ __launch_bounds__(256) void k_prep(const float* __restrict__ gcw,
                                              unsigned short* __restrict__ gcwT,
                                              const float* __restrict__ imgf,
                                              const float* __restrict__ bbox,
                                              const float* __restrict__ lw,
                                              const float* __restrict__ lb,
                                              const int* __restrict__ labels,
                                              unsigned short* __restrict__ xbf,
                                              const float* __restrict__ X,
                                              const float* __restrict__ adj,
                                              unsigned short* __restrict__ A2p) {
  __shared__ float smf[64 * 65];   // 16.6 KB; buildx aliases lab/sidx/swt onto it
  const int bx  = blockIdx.x;
  const int tid = threadIdx.x;

  if (bx < 768) {
    // ---- buildx role ----
    int*   lab  = (int*)smf;           // [150]
    int*   sidx = lab + NBPER;         // [100][3]
    float* swt  = (float*)(sidx + 3 * CC);  // [100][3]
    const int bimg = bx / 12;
    const int sl   = bx - bimg * 12;   // cols [sl*22, sl*22+22)
    if (tid < NBPER) lab[tid] = labels[bimg * NBPER + tid];
    __syncthreads();
    if (tid < CC) {                    // parallel stable scan, branchless output
      int i0 = 0, i1 = 0, i2 = 0, cnt = 0;
      float w0 = 0.f, w1 = 0.f, w2 = 0.f;
      for (int i = 0; i < NBPER; ++i) {
        if (lab[i] == tid + 1) {
          if (cnt == 0)      { i0 = bimg * NBPER + i; w0 = lw[0]; }
          else if (cnt == 1) { i1 = bimg * NBPER + i; w1 = lw[1]; }
          else if (cnt == 2) { i2 = bimg * NBPER + i; w2 = lw[2]; }
          ++cnt;
        }
      }
      sidx[tid * 3] = i0; sidx[tid * 3 + 1] = i1; sidx[tid * 3 + 2] = i2;
      swt[tid * 3] = w0;  swt[tid * 3 + 1] = w1;  swt[tid * 3 + 2] = w2;
    }
    __syncthreads();
    const float bias = lb[0];
    for (int idx = tid; idx < CC * 22; idx += 256) {
      const int cl  = idx / 22;
      const int col = sl * 22 + (idx - cl * 22);   // 0..263
      const int d0  = col * 8;
      const int r   = bimg * CC + cl;
      const int i0 = sidx[cl * 3], i1 = sidx[cl * 3 + 1], i2 = sidx[cl * 3 + 2];
      const float w0 = swt[cl * 3], w1 = swt[cl * 3 + 1], w2 = swt[cl * 3 + 2];
      float v[8];
      if (d0 < 2048) {
        // 6 unconditional, independent loads (full MLP), then FMA
        const float4* p0 = (const float4*)(imgf + (size_t)i0 * 2048 + d0);
        const float4* p1 = (const float4*)(imgf + (size_t)i1 * 2048 + d0);
        const float4* p2 = (const float4*)(imgf + (size_t)i2 * 2048 + d0);
        float4 a0 = p0[0], a1 = p0[1];
        float4 b0 = p1[0], b1 = p1[1];
        float4 c0 = p2[0], c1 = p2[1];
        v[0] = bias + w0 * a0.x + w1 * b0.x + w2 * c0.x;
        v[1] = bias + w0 * a0.y + w1 * b0.y + w2 * c0.y;
        v[2] = bias + w0 * a0.z + w1 * b0.z + w2 * c0.z;
        v[3] = bias + w0 * a0.w + w1 * b0.w + w2 * c0.w;
        v[4] = bias + w0 * a1.x + w1 * b1.x + w2 * c1.x;
        v[5] = bias + w0 * a1.y + w1 * b1.y + w2 * c1.y;
        v[6] = bias + w0 * a1.z + w1 * b1.z + w2 * c1.z;
        v[7] = bias + w0 * a1.w + w1 * b1.w + w2 * c1.w;
      } else if (d0 == 2048) {
        float4 u0 = *(const float4*)(bbox + (size_t)i0 * 4);
        float4 u1 = *(const float4*)(bbox + (size_t)i1 * 4);
        float4 u2 = *(const float4*)(bbox + (size_t)i2 * 4);
        v[0] = bias + w0 * u0.x + w1 * u1.x + w2 * u2.x;
        v[1] = bias + w0 * u0.y + w1 * u1.y + w2 * u2.y;
        v[2] = bias + w0 * u0.z + w1 * u1.z + w2 * u2.z;
        v[3] = bias + w0 * u0.w + w1 * u1.w + w2 * u2.w;
        v[4] = 0.f; v[5] = 0.f; v[6] = 0.f; v[7] = 0.f;
      } else {
#pragma unroll
        for (int q = 0; q < 8; ++q) v[q] = 0.f;
      }
      unsigned short o[8] __attribute__((aligned(16)));
#pragma unroll
      for (int q = 0; q < 8; ++q) o[q] = f2bf(v[q]);
      *(uint4*)(xbf + (size_t)r * KP + d0) = *(const uint4*)o;
    }
    return;
  }

  if (bx < 1824) {
    // ---- transpose role: 64x64 tile ----
    const int t  = bx - 768;       // 0..1055
    const int ko = t % 33;
    const int oo = t / 33;
    const int cc = tid & 63, r0 = tid >> 6;
#pragma unroll
    for (int i = 0; i < 16; ++i) {
      const int r = r0 * 16 + i;
      const int k = ko * 64 + r;
      smf[r * 65 + cc] = (k < FEAT) ? gcw[(size_t)k * NOUT + oo * 64 + cc] : 0.f;
    }
    __syncthreads();
    const int ol = tid >> 2;       // 0..63
    const int kq = tid & 3;        // covers 16 k's
    unsigned short buf[16] __attribute__((aligned(16)));
#pragma unroll
    for (int j = 0; j < 16; ++j) buf[j] = f2bf(smf[(kq * 16 + j) * 65 + ol]);
    const size_t base = (size_t)(oo * 64 + ol) * KP + ko * 64 + kq * 16;
    *(uint4*)&gcwT[base]     = *(const uint4*)&buf[0];
    *(uint4*)&gcwT[base + 8] = *(const uint4*)&buf[8];
    return;
  }

  // ---- A2p role ----
  {
    const int b = bx - 1824;
#pragma unroll
    for (int it = 0; it < 16; ++it) {
      const int idx = it * 256 + tid;
      const int c = idx >> 5, ng = idx & 31;
      const int n = ng * 4;
      unsigned short pk[4] __attribute__((aligned(8))) = {0, 0, 0, 0};
      if (c < CC && n < CC) {   // n multiple of 4 -> n+3 <= 99
        const float4 a4 = *(const float4*)(adj + (size_t)b * (CC * CC) + c * CC + n);
        const float4 x4 = *(const float4*)(X + c * CC + n);
        pk[0] = f2bf(a4.x + x4.x); pk[1] = f2bf(a4.y + x4.y);
        pk[2] = f2bf(a4.z + x4.z); pk[3] = f2bf(a4.w + x4.w);
      }
      *(uint2*)&A2p[((size_t)b * 128 + c) * 128 + n] = *(const uint2*)pk;
    }
  }
}

// ---------------------------------------------------------------------------
// KC: support = x_bf16 @ gcwT^T -> supportT[b][o][n pad 128] bf16.
// R4-proven structure: async16 staging, 2-barrier K-loop (NO VGPR prefetch --
// spilled in R3 and R5 regardless of launch_bounds), XCD swizzle,
// LDS-transpose epilogue. FROZEN since R7.
// ---------------------------------------------------------------------------
__global__ __launch_bounds__(256) void k_gemm1(const unsigned short* __restrict__ A,
                                               const unsigned short* __restrict__ Bt,
                                               unsigned short* __restrict__ ST) {
  __shared__ unsigned short shbuf[128 * 132] __attribute__((aligned(16)));  // 33.8 KB
  unsigned short* Asm = shbuf;          // staging: 8192 ushorts
  unsigned short* Bsm = shbuf + 8192;   //          8192 ushorts
  const int tid  = threadIdx.x;
  const int lane = tid & 63;
  const int w    = tid >> 6;
  const int v    = blockIdx.y * gridDim.x + blockIdx.x;  // 0..799
  const int ncol = (v & 7) * 2 + ((v >> 3) & 1);
  const int mrow = v >> 4;
  const int m0   = mrow * 128;
  const int n0   = ncol * 128;
  const int wm   = (w & 1) * 64;
  const int wn   = (w >> 1) * 64;
  const int srow = lane >> 3;                      // row within 8-row chunk (== m&7)
  const int gk   = (((lane & 7) - srow) & 7) * 8;  // swizzle-inverse k start
  const int quad = lane >> 4;
  const int lrow = lane & 15;
  const int rot  = (lane & 7) * 8;

  floatx4 acc[4][4] = {};

  for (int kb = 0; kb < KP / 64; ++kb) {
    const int k0 = kb * 64;
#pragma unroll
    for (int t = 0; t < 4; ++t) {
      const int chunk = t * 4 + w;
      const int row = chunk * 8 + srow;
      async16(A  + (size_t)(m0 + row) * KP + (k0 + gk), &Asm[chunk * 512]);
      async16(Bt + (size_t)(n0 + row) * KP + (k0 + gk), &Bsm[chunk * 512]);
    }
    __syncthreads();  // drains vmcnt + barrier
#pragma unroll
    for (int kp = 0; kp < 2; ++kp) {
      const int koff = (kp * 32 + quad * 8 + rot) & 63;
      short8 af[4], bfr[4];
#pragma unroll
      for (int i = 0; i < 4; ++i)
        af[i]  = *(const short8*)&Asm[(wm + i * 16 + lrow) * 64 + koff];
#pragma unroll
      for (int j = 0; j < 4; ++j)
        bfr[j] = *(const short8*)&Bsm[(wn + j * 16 + lrow) * 64 + koff];
#pragma unroll
      for (int i = 0; i < 4; ++i)
#pragma unroll
        for (int j = 0; j < 4; ++j)
          acc[i][j] = __builtin_amdgcn_mfma_f32_16x16x32_bf16(af[i], bfr[j], acc[i][j], 0, 0, 0);
    }
    __syncthreads();
  }

  // epilogue: acc(row=m_local, col=o_local) -> LDS T[o][m] (stride 132), then
  // coalesced uint stores into ST[b][n0+o][c] (c,c+1 never straddle b: m0 even).
#pragma unroll
  for (int j = 0; j < 4; ++j) {
    const int ol = wn + j * 16 + lrow;
#pragma unroll
    for (int i = 0; i < 4; ++i) {
#pragma unroll
      for (int rr = 0; rr < 4; ++rr) {
        const int ml = wm + i * 16 + quad * 4 + rr;
        shbuf[ol * 132 + ml] = f2bf(acc[i][j][rr]);
      }
    }
  }
  __syncthreads();
#pragma unroll
  for (int it = 0; it < 32; ++it) {
    const int idx = it * 256 + tid;
    const int o = idx >> 6;          // 0..127
    const int cp = idx & 63;         // c-pair
    const int m = 2 * cp;
    const int r = m0 + m;
    const int b = r / 100;           // magic-mul
    const int c = r - b * 100;       // even; (c,c+1) same b
    const unsigned int val = *(const unsigned int*)&shbuf[o * 132 + m];
    *(unsigned int*)&ST[((size_t)b * NOUT + n0 + o) * 128 + c] = val;
  }
}

// ---------------------------------------------------------------------------
// KD: out[b,o] = sum_c g[b,c]*lrelu( sum_n A2[c,n] * S[b,n,o] + gc_b[o] )
// bf16 MFMA; BOTH operands async16-staged from pre-packed A2p / supportT.
// ST pad n>=100 may be garbage; A2p cols are zero there so products vanish.
// FROZEN since R7.
// ---------------------------------------------------------------------------
__global__ __launch_bounds__(256) void k_gemm2(const unsigned short* __restrict__ A2p,
                                               const unsigned short* __restrict__ ST,
                                               const float* __restrict__ gf,
                                               const float* __restrict__ gcb,
                                               float* __restrict__ outp) {
  __shared__ unsigned short A2s[128 * 64] __attribute__((aligned(16)));
  __shared__ unsigned short Ssm[128 * 64] __attribute__((aligned(16)));
  __shared__ float gsm[128];
  __shared__ float red[128 * 9];
  const int tid = threadIdx.x;
  const int o0  = blockIdx.x * 128;
  const int b   = blockIdx.y;
  if (tid < 128) gsm[tid] = (tid < CC) ? gf[b * CC + tid] : 0.f;

  const int lane = tid & 63;
  const int w    = tid >> 6;
  const int srow = lane >> 3;
  const int gk   = (((lane & 7) - srow) & 7) * 8;
  const int quad = lane >> 4;
  const int lrow = lane & 15;
  const int rot  = (lane & 7) * 8;
  const int wm   = (w & 1) * 64;
  const int wn   = (w >> 1) * 64;

  floatx4 acc[4][4] = {};

  for (int kb = 0; kb < 2; ++kb) {
    const int k0 = kb * 64;
    __syncthreads();  // protect LDS reuse across kb (and gsm ordering)
#pragma unroll
    for (int t = 0; t < 4; ++t) {
      const int chunk = t * 4 + w;
      const int row = chunk * 8 + srow;
      async16(A2p + ((size_t)b * 128 + row) * 128 + k0 + gk, &A2s[chunk * 512]);
      async16(ST + ((size_t)b * NOUT + o0 + row) * 128 + k0 + gk, &Ssm[chunk * 512]);
    }
    __syncthreads();
#pragma unroll
    for (int kp = 0; kp < 2; ++kp) {
      const int koff = (kp * 32 + quad * 8 + rot) & 63;
      short8 af[4], bfr[4];
#pragma unroll
      for (int i = 0; i < 4; ++i)
        af[i]  = *(const short8*)&A2s[(wm + i * 16 + lrow) * 64 + koff];
#pragma unroll
      for (int j = 0; j < 4; ++j)
        bfr[j] = *(const short8*)&Ssm[(wn + j * 16 + lrow) * 64 + koff];
#pragma unroll
      for (int i = 0; i < 4; ++i)
#pragma unroll
        for (int j = 0; j < 4; ++j)
          acc[i][j] = __builtin_amdgcn_mfma_f32_16x16x32_bf16(af[i], bfr[j], acc[i][j], 0, 0, 0);
    }
  }
  __syncthreads();

  // epilogue: out_o = sum_c g[c]*lrelu(T[c][o]+bias[o])
  const int slot = (w & 1) * 4 + quad;
#pragma unroll
  for (int j = 0; j < 4; ++j) {
    const int ol = wn + j * 16 + lrow;
    const float bias = gcb[o0 + ol];
    float s = 0.f;
#pragma unroll
    for (int i = 0; i < 4; ++i) {
#pragma unroll
      for (int rr = 0; rr < 4; ++rr) {
        const int c = wm + i * 16 + quad * 4 + rr;
        float t = acc[i][j][rr] + bias;
        t = (t > 0.f) ? t : 0.01f * t;
        s += gsm[c] * t;   // gsm[c]=0 masks c>=100 pad rows
      }
    }
    red[ol * 9 + slot] = s;
  }
  __syncthreads();
  if (tid < 128) {
    float s = 0.f;
#pragma unroll
    for (int t = 0; t < 8; ++t) s += red[tid * 9 + t];
    outp[(size_t)b * NOUT + o0 + tid] = s;
  }
}

// ---------------------------------------------------------------------------
extern "C" void kernel_launch(void* const* d_in, const int* in_sizes, int n_in,
                              void* d_out, int out_size, void* d_ws, size_t ws_size,
                              hipStream_t stream) {
  const float* imgf   = (const float*)d_in[0];
  const float* bbox   = (const float*)d_in[1];
  const float* gfeat  = (const float*)d_in[2];
  const float* adj    = (const float*)d_in[3];
  const float* X      = (const float*)d_in[4];
  const float* lw     = (const float*)d_in[5];
  const float* lb     = (const float*)d_in[6];
  const float* gcw    = (const float*)d_in[7];
  const float* gcb    = (const float*)d_in[8];
  const int*   labels = (const int*)d_in[9];

  char* ws = (char*)d_ws;
  // ws layout (~71.3 MB; ST must NOT overlay xbf -- gemm1 reads xbf while
  // writing ST):
  //   [0, 27,033,600)             xbf
  //   [27,033,600, 35,684,352)    gcwT
  //   [35,684,352, 69,238,784)    supportT [64][2048][128] bf16
  //   [69,238,784, 71,335,936)    A2p      [64][128][128] bf16
  unsigned short* xbf      = (unsigned short*)(ws);
  unsigned short* gcwT     = (unsigned short*)(ws + 27033600);
  unsigned short* supportT = (unsigned short*)(ws + 35684352);
  unsigned short* A2p      = (unsigned short*)(ws + 69238784);
  float*          outp     = (float*)d_out;

  k_prep<<<dim3(1888), dim3(256), 0, stream>>>(gcw, gcwT, imgf, bbox, lw, lb,
                                               labels, xbf, X, adj, A2p);
  k_gemm1<<<dim3(16, 50), dim3(256), 0, stream>>>(xbf, gcwT, supportT);
  k_gemm2<<<dim3(NOUT / 128, BB), dim3(256), 0, stream>>>(A2p, supportT, gfeat, gcb, outp);
}